// Round 9
// baseline (394.801 us; speedup 1.0000x reference)
//
#include <hip/hip_runtime.h>
#include <math.h>

#define TPB 256

typedef unsigned long long u64;
typedef unsigned int u32;
// Clang ext vector for __builtin_nontemporal_load (emits global_load_dwordx4 nt).
typedef float f4 __attribute__((ext_vector_type(4)));

// Packed sort key: strictly increasing in value; ties -> smaller index wins.
// u64 compare (>) == better(v1,i1,v2,i2) from jnp.argsort(-scores) stability.
__device__ __forceinline__ u64 mkkey(float v, int idx) {
    u32 u = __float_as_uint(v);
    u ^= (u32)(((int)u) >> 31) | 0x80000000u;   // monotone float->uint map
    return ((u64)u << 32) | (u32)(~idx);
}

// Branchless top-5 update on named u64 scalars (k0 >= k1 >= ... >= k4).
#define UPD(v, idx)                                             \
    {                                                           \
        const u64 _key = mkkey((v), (idx));                     \
        const bool c0 = _key > k0;                              \
        const bool c1 = _key > k1;                              \
        const bool c2 = _key > k2;                              \
        const bool c3 = _key > k3;                              \
        const bool c4 = _key > k4;                              \
        k4 = c3 ? k3 : (c4 ? _key : k4);                        \
        k3 = c2 ? k2 : (c3 ? _key : k3);                        \
        k2 = c1 ? k1 : (c2 ? _key : k2);                        \
        k1 = c0 ? k0 : (c1 ? _key : k1);                        \
        k0 = c0 ? _key : k0;                                    \
    }

// Key-only branchless ladder (finalize phase).
#define UPDK(key)                                               \
    {                                                           \
        const u64 _key = (key);                                 \
        const bool c0 = _key > k0;                              \
        const bool c1 = _key > k1;                              \
        const bool c2 = _key > k2;                              \
        const bool c3 = _key > k3;                              \
        const bool c4 = _key > k4;                              \
        k4 = c3 ? k3 : (c4 ? _key : k4);                        \
        k3 = c2 ? k2 : (c3 ? _key : k3);                        \
        k2 = c1 ? k1 : (c2 ? _key : k2);                        \
        k1 = c0 ? k0 : (c1 ? _key : k1);                        \
        k0 = c0 ? _key : k0;                                    \
    }

// Process one quad already in registers. Fully branchless.
#define PROC(p, t, r, qi)                                                   \
    {                                                                       \
        float d;                                                            \
        d = p.x - t.x; accb = fmaf(d, d, accb);                             \
        d = p.y - t.y; accb = fmaf(d, d, accb);                             \
        d = p.z - t.z; accb = fmaf(d, d, accb);                             \
        d = p.w - t.w; accb = fmaf(d, d, accb);                             \
        accr += (r.x >= 2.0f ? r.x : 0.0f) + (r.y >= 2.0f ? r.y : 0.0f)     \
              + (r.z >= 2.0f ? r.z : 0.0f) + (r.w >= 2.0f ? r.w : 0.0f);    \
        const int _b = (qi) * 4;                                            \
        UPD(p.x, _b);                                                       \
        UPD(p.y, _b + 1);                                                   \
        UPD(p.z, _b + 2);                                                   \
        UPD(p.w, _b + 3);                                                   \
    }

#define NTLOAD(ptr) __builtin_nontemporal_load(ptr)

// Fused: R6-style interleaved all-nt streaming + last-block-done finalize
// (two-phase reduction, counter zeroed by hipMemsetAsync each call).
__global__ __launch_bounds__(TPB) void reward_fused(
        const float* __restrict__ pred,
        const float* __restrict__ tru,
        const float* __restrict__ ret,
        double* __restrict__ blk_sum,
        u64* __restrict__ cand_k,
        u32* __restrict__ counter,
        float* __restrict__ out,
        int n, int nb) {
    const int tid = blockIdx.x * blockDim.x + threadIdx.x;
    const int nthreads = gridDim.x * blockDim.x;
    const int n4 = n >> 2;

    const f4* __restrict__ pred4 = (const f4*)pred;
    const f4* __restrict__ tru4  = (const f4*)tru;
    const f4* __restrict__ ret4  = (const f4*)ret;

    float accb = 0.0f;   // sum of (pred-true)^2
    float accr = 0.0f;   // sum of ret where ret >= 2 (rest_adj = 0.0015 * that)
    u64 k0 = 0, k1 = 0, k2 = 0, k3 = 0, k4 = 0;  // real keys are always > 0

    // All-nt (the R6 win: cached miss path serves ~2.8 TB/s, nt ~4.6 TB/s),
    // interleaved grid-stride (best of the indexing variants).
    int i = tid;
    for (; i + 3 * nthreads < n4; i += 4 * nthreads) {
        const int ia = i;
        const int ib = i + nthreads;
        const int ic = i + 2 * nthreads;
        const int id = i + 3 * nthreads;
        f4 pa = NTLOAD(pred4 + ia), pb = NTLOAD(pred4 + ib),
           pc = NTLOAD(pred4 + ic), pd = NTLOAD(pred4 + id);
        f4 ta = NTLOAD(tru4 + ia),  tb = NTLOAD(tru4 + ib),
           tc = NTLOAD(tru4 + ic),  td = NTLOAD(tru4 + id);
        f4 ra = NTLOAD(ret4 + ia),  rb = NTLOAD(ret4 + ib),
           rc = NTLOAD(ret4 + ic),  rd = NTLOAD(ret4 + id);
        PROC(pa, ta, ra, ia)
        PROC(pb, tb, rb, ib)
        PROC(pc, tc, rc, ic)
        PROC(pd, td, rd, id)
    }
    for (; i < n4; i += nthreads) {
        const f4 p = NTLOAD(pred4 + i);
        const f4 t = NTLOAD(tru4 + i);
        const f4 r = NTLOAD(ret4 + i);
        PROC(p, t, r, i)
    }

    // Scalar tail (n not multiple of 4), handled by global thread 0.
    if (tid == 0) {
        for (int kk = n4 * 4; kk < n; ++kk) {
            float d = pred[kk] - tru[kk];
            accb = fmaf(d, d, accb);
            float rr = ret[kk];
            accr += (rr >= 2.0f ? rr : 0.0f);
            UPD(pred[kk], kk);
        }
    }

    const int lane = threadIdx.x & 63;
    const int wid  = threadIdx.x >> 6;

    // Block sum: wave shuffle reduce (double), then 4 wave partials via LDS.
    double acc = (double)accb + 0.0015 * (double)accr;
    for (int off = 32; off > 0; off >>= 1) acc += __shfl_down(acc, off);
    __shared__ double wsum[4];
    if (lane == 0) wsum[wid] = acc;
    __syncthreads();
    if (threadIdx.x == 0)
        blk_sum[blockIdx.x] = wsum[0] + wsum[1] + wsum[2] + wsum[3];

    // Block top-5: 5 rounds of (wave shfl argmax on keys -> cross-wave -> pop).
    __shared__ u64 bsk[4];
    for (int r = 0; r < 5; ++r) {
        const u64 ck = k0;
        u64 wk = ck;
        for (int off = 1; off < 64; off <<= 1) {
            u64 ok = __shfl_xor(wk, off);
            if (ok > wk) wk = ok;
        }
        if (lane == 0) bsk[wid] = wk;
        __syncthreads();
        u64 gk = bsk[0];
        if (bsk[1] > gk) gk = bsk[1];
        if (bsk[2] > gk) gk = bsk[2];
        if (bsk[3] > gk) gk = bsk[3];
        if (threadIdx.x == 0) cand_k[blockIdx.x * 5 + r] = gk;
        if (gk == ck) {  // keys unique -> exactly one owner pops
            k0 = k1; k1 = k2; k2 = k3; k3 = k4; k4 = 0;
        }
        __syncthreads();  // WAR: bsk reused next round
    }

    // ---- last-block-done finalize (replaces the second kernel) ----
    __shared__ bool amLast;
    __threadfence();   // make blk_sum/cand_k writes visible device-wide
    if (threadIdx.x == 0)
        amLast = (atomicAdd(counter, 1u) == (u32)(nb - 1));
    __syncthreads();
    if (!amLast) return;

    // Sum of partials (double2 16B loads; nb is a power of two >= 64).
    double facc = 0.0;
    const double2* __restrict__ bs2 = (const double2*)blk_sum;
    const int nb2 = nb >> 1;
    for (int ii = threadIdx.x; ii < nb2; ii += TPB) {
        double2 v = bs2[ii];
        facc += v.x + v.y;
    }
    for (int off = 32; off > 0; off >>= 1) facc += __shfl_down(facc, off);
    __syncthreads();   // wsum reused
    if (lane == 0) wsum[wid] = facc;
    __syncthreads();

    // Per-thread top-5 over all candidate keys, 2 keys per 16B load.
    k0 = 0; k1 = 0; k2 = 0; k3 = 0; k4 = 0;
    const ulonglong2* __restrict__ ck2 = (const ulonglong2*)cand_k;
    const int npairs = (nb * 5) >> 1;   // nb even -> exact
    for (int ii = threadIdx.x; ii < npairs; ii += TPB) {
        const ulonglong2 kp = ck2[ii];
        UPDK(kp.x)
        UPDK(kp.y)
    }

    // 5 rounds block argmax + pop -> global top-5 indices.
    __shared__ int winner[5];
    for (int r = 0; r < 5; ++r) {
        const u64 ck = k0;
        u64 wk = ck;
        for (int off = 1; off < 64; off <<= 1) {
            u64 ok = __shfl_xor(wk, off);
            if (ok > wk) wk = ok;
        }
        if (lane == 0) bsk[wid] = wk;
        __syncthreads();
        u64 gk = bsk[0];
        if (bsk[1] > gk) gk = bsk[1];
        if (bsk[2] > gk) gk = bsk[2];
        if (bsk[3] > gk) gk = bsk[3];
        if (threadIdx.x == 0) winner[r] = (int)(~(u32)gk);
        if (gk == ck) {
            k0 = k1; k1 = k2; k2 = k3; k3 = k4; k4 = 0;
        }
        __syncthreads();
    }

    if (threadIdx.x == 0) {
        double tot = wsum[0] + wsum[1] + wsum[2] + wsum[3];
        double corr = 0.0;
        for (int r = 0; r < 5; ++r) {
            int idx = winner[r];
            float rr = ret[idx];
            float a = fabsf(rr);
            float strict, mid;
            if (rr < 0.0f)       { strict = 0.005f * a;  mid = 0.0025f * a; }
            else if (rr >= 2.0f) { strict = -0.02f * rr; mid = -0.01f * rr; }
            else if (rr > 0.0f)  { strict = -0.01f * rr; mid = -0.005f * rr; }
            else                 { strict = 0.0f;        mid = 0.0f; }
            float rest = (rr >= 2.0f) ? 0.0015f * rr : 0.0f;
            float bucket = (r < 3) ? strict : mid;  // ranks 1..3 strict, 4..5 mid
            corr += (double)(bucket - rest);
        }
        out[0] = (float)((tot + corr) / (double)n);
    }
}

extern "C" void kernel_launch(void* const* d_in, const int* in_sizes, int n_in,
                              void* d_out, int out_size, void* d_ws, size_t ws_size,
                              hipStream_t stream) {
    const float* pred = (const float*)d_in[0];
    const float* tru  = (const float*)d_in[1];
    const float* ret  = (const float*)d_in[2];
    float* out = (float*)d_out;
    const int n = in_sizes[0];

    int nb = 2048;
    // ws layout: [counter 16B][blk_sum nb*8B][cand_k nb*40B]; nb even so
    // cand_k stays 16B-aligned for ulonglong2 loads.
    while (nb > 64 && (size_t)nb * 48 + 16 > ws_size) nb >>= 1;

    u32*    counter = (u32*)d_ws;
    double* blk_sum = (double*)((char*)d_ws + 16);
    u64*    cand_k  = (u64*)(blk_sum + nb);

    // Zero the arrival counter each call (graph-capture-safe async memset;
    // d_ws is poisoned 0xAA once and never re-poisoned between replays).
    hipMemsetAsync(counter, 0, sizeof(u32), stream);
    reward_fused<<<nb, TPB, 0, stream>>>(pred, tru, ret, blk_sum, cand_k,
                                         counter, out, n, nb);
}

// Round 10
// 49.610 us; speedup vs baseline: 7.9580x; 7.9580x over previous
//
#include <hip/hip_runtime.h>
#include <math.h>

#define TPB 256

typedef unsigned long long u64;
typedef unsigned int u32;
// Clang ext vector for __builtin_nontemporal_load (emits global_load_dwordx4 nt).
typedef float f4 __attribute__((ext_vector_type(4)));

// Packed sort key: strictly increasing in value; ties -> smaller index wins.
// u64 compare (>) == better(v1,i1,v2,i2) from jnp.argsort(-scores) stability.
__device__ __forceinline__ u64 mkkey(float v, int idx) {
    u32 u = __float_as_uint(v);
    u ^= (u32)(((int)u) >> 31) | 0x80000000u;   // monotone float->uint map
    return ((u64)u << 32) | (u32)(~idx);
}

// Branchless top-5 update on named u64 scalars (k0 >= k1 >= ... >= k4).
#define UPD(v, idx)                                             \
    {                                                           \
        const u64 _key = mkkey((v), (idx));                     \
        const bool c0 = _key > k0;                              \
        const bool c1 = _key > k1;                              \
        const bool c2 = _key > k2;                              \
        const bool c3 = _key > k3;                              \
        const bool c4 = _key > k4;                              \
        k4 = c3 ? k3 : (c4 ? _key : k4);                        \
        k3 = c2 ? k2 : (c3 ? _key : k3);                        \
        k2 = c1 ? k1 : (c2 ? _key : k2);                        \
        k1 = c0 ? k0 : (c1 ? _key : k1);                        \
        k0 = c0 ? _key : k0;                                    \
    }

// Process one quad already in registers. Fully branchless.
#define PROC(p, t, r, qi)                                                   \
    {                                                                       \
        float d;                                                            \
        d = p.x - t.x; accb = fmaf(d, d, accb);                             \
        d = p.y - t.y; accb = fmaf(d, d, accb);                             \
        d = p.z - t.z; accb = fmaf(d, d, accb);                             \
        d = p.w - t.w; accb = fmaf(d, d, accb);                             \
        accr += (r.x >= 2.0f ? r.x : 0.0f) + (r.y >= 2.0f ? r.y : 0.0f)     \
              + (r.z >= 2.0f ? r.z : 0.0f) + (r.w >= 2.0f ? r.w : 0.0f);    \
        const int _b = (qi) * 4;                                            \
        UPD(p.x, _b);                                                       \
        UPD(p.y, _b + 1);                                                   \
        UPD(p.z, _b + 2);                                                   \
        UPD(p.w, _b + 3);                                                   \
    }

#define NTLOAD(ptr) __builtin_nontemporal_load(ptr)

// Pass 1: R6 interleaved all-nt streaming (best measured: ~44 us).
// NO device-scope fences anywhere in this kernel (R9 lesson: 8192 wave-level
// __threadfence L2-invalidates serialized the whole chip, 44 -> 385 us).
__global__ __launch_bounds__(TPB) void reward_pass1(
        const float* __restrict__ pred,
        const float* __restrict__ tru,
        const float* __restrict__ ret,
        double* __restrict__ blk_sum,
        u64* __restrict__ cand_k,
        int n) {
    const int tid = blockIdx.x * blockDim.x + threadIdx.x;
    const int nthreads = gridDim.x * blockDim.x;
    const int n4 = n >> 2;

    const f4* __restrict__ pred4 = (const f4*)pred;
    const f4* __restrict__ tru4  = (const f4*)tru;
    const f4* __restrict__ ret4  = (const f4*)ret;

    float accb = 0.0f;   // sum of (pred-true)^2
    float accr = 0.0f;   // sum of ret where ret >= 2 (rest_adj = 0.0015 * that)
    u64 k0 = 0, k1 = 0, k2 = 0, k3 = 0, k4 = 0;  // real keys are always > 0

    int i = tid;
    for (; i + 3 * nthreads < n4; i += 4 * nthreads) {
        const int ia = i;
        const int ib = i + nthreads;
        const int ic = i + 2 * nthreads;
        const int id = i + 3 * nthreads;
        f4 pa = NTLOAD(pred4 + ia), pb = NTLOAD(pred4 + ib),
           pc = NTLOAD(pred4 + ic), pd = NTLOAD(pred4 + id);
        f4 ta = NTLOAD(tru4 + ia),  tb = NTLOAD(tru4 + ib),
           tc = NTLOAD(tru4 + ic),  td = NTLOAD(tru4 + id);
        f4 ra = NTLOAD(ret4 + ia),  rb = NTLOAD(ret4 + ib),
           rc = NTLOAD(ret4 + ic),  rd = NTLOAD(ret4 + id);
        PROC(pa, ta, ra, ia)
        PROC(pb, tb, rb, ib)
        PROC(pc, tc, rc, ic)
        PROC(pd, td, rd, id)
    }
    for (; i < n4; i += nthreads) {
        const f4 p = NTLOAD(pred4 + i);
        const f4 t = NTLOAD(tru4 + i);
        const f4 r = NTLOAD(ret4 + i);
        PROC(p, t, r, i)
    }

    // Scalar tail (n not multiple of 4), handled by global thread 0.
    if (tid == 0) {
        for (int kk = n4 * 4; kk < n; ++kk) {
            float d = pred[kk] - tru[kk];
            accb = fmaf(d, d, accb);
            float rr = ret[kk];
            accr += (rr >= 2.0f ? rr : 0.0f);
            UPD(pred[kk], kk);
        }
    }

    const int lane = threadIdx.x & 63;
    const int wid  = threadIdx.x >> 6;

    // Block sum: wave shuffle reduce (double), then 4 wave partials via LDS.
    double acc = (double)accb + 0.0015 * (double)accr;
    for (int off = 32; off > 0; off >>= 1) acc += __shfl_down(acc, off);
    __shared__ double wsum[4];
    if (lane == 0) wsum[wid] = acc;
    __syncthreads();
    if (threadIdx.x == 0)
        blk_sum[blockIdx.x] = wsum[0] + wsum[1] + wsum[2] + wsum[3];

    // Block top-5: 5 rounds of (wave shfl argmax on keys -> cross-wave -> pop).
    __shared__ u64 bsk[4];
    for (int r = 0; r < 5; ++r) {
        const u64 ck = k0;
        u64 wk = ck;
        for (int off = 1; off < 64; off <<= 1) {
            u64 ok = __shfl_xor(wk, off);
            if (ok > wk) wk = ok;
        }
        if (lane == 0) bsk[wid] = wk;
        __syncthreads();
        u64 gk = bsk[0];
        if (bsk[1] > gk) gk = bsk[1];
        if (bsk[2] > gk) gk = bsk[2];
        if (bsk[3] > gk) gk = bsk[3];
        if (threadIdx.x == 0) cand_k[blockIdx.x * 5 + r] = gk;
        if (gk == ck) {  // keys unique -> exactly one owner pops
            k0 = k1; k1 = k2; k2 = k3; k3 = k4; k4 = 0;
        }
        __syncthreads();  // WAR: bsk reused next round
    }
}

// Pass 2: 1024 threads (16 waves) + 16B vector reads (R7 version, ~2-3 us).
#define TPB2 1024
__global__ __launch_bounds__(TPB2) void reward_pass2(
        const double* __restrict__ blk_sum,
        const u64* __restrict__ cand_k,
        const float* __restrict__ ret,
        float* __restrict__ out,
        int nb, int n) {
    const int lane = threadIdx.x & 63;
    const int wid  = threadIdx.x >> 6;   // 0..15

    // Sum of partials (double2 = 16B loads; nb is a power of two >= 64).
    double acc = 0.0;
    const double2* __restrict__ bs2 = (const double2*)blk_sum;
    const int nb2 = nb >> 1;
    for (int i = threadIdx.x; i < nb2; i += TPB2) {
        double2 v = bs2[i];
        acc += v.x + v.y;
    }
    for (int off = 32; off > 0; off >>= 1) acc += __shfl_down(acc, off);
    __shared__ double wsum[16];
    if (lane == 0) wsum[wid] = acc;
    __syncthreads();

    // Per-thread top-5 over candidate keys, 2 keys per 16B load.
    u64 k0 = 0, k1 = 0, k2 = 0, k3 = 0, k4 = 0;
    const ulonglong2* __restrict__ ck2 = (const ulonglong2*)cand_k;
    const int npairs = (nb * 5) >> 1;   // nb even -> exact
    for (int i = threadIdx.x; i < npairs; i += TPB2) {
        const ulonglong2 kp = ck2[i];
        {
            const u64 _key = kp.x;
            const bool c0 = _key > k0; const bool c1 = _key > k1;
            const bool c2 = _key > k2; const bool c3 = _key > k3;
            const bool c4 = _key > k4;
            k4 = c3 ? k3 : (c4 ? _key : k4);
            k3 = c2 ? k2 : (c3 ? _key : k3);
            k2 = c1 ? k1 : (c2 ? _key : k2);
            k1 = c0 ? k0 : (c1 ? _key : k1);
            k0 = c0 ? _key : k0;
        }
        {
            const u64 _key = kp.y;
            const bool c0 = _key > k0; const bool c1 = _key > k1;
            const bool c2 = _key > k2; const bool c3 = _key > k3;
            const bool c4 = _key > k4;
            k4 = c3 ? k3 : (c4 ? _key : k4);
            k3 = c2 ? k2 : (c3 ? _key : k3);
            k2 = c1 ? k1 : (c2 ? _key : k2);
            k1 = c0 ? k0 : (c1 ? _key : k1);
            k0 = c0 ? _key : k0;
        }
    }

    // 5 rounds block argmax + pop -> global top-5 indices.
    __shared__ u64 bsk[16];
    __shared__ int winner[5];
    for (int r = 0; r < 5; ++r) {
        const u64 ck = k0;
        u64 wk = ck;
        for (int off = 1; off < 64; off <<= 1) {
            u64 ok = __shfl_xor(wk, off);
            if (ok > wk) wk = ok;
        }
        if (lane == 0) bsk[wid] = wk;
        __syncthreads();
        u64 gk = bsk[0];
#pragma unroll
        for (int w = 1; w < 16; ++w)
            if (bsk[w] > gk) gk = bsk[w];
        if (threadIdx.x == 0) winner[r] = (int)(~(u32)gk);
        if (gk == ck) {
            k0 = k1; k1 = k2; k2 = k3; k3 = k4; k4 = 0;
        }
        __syncthreads();
    }

    if (threadIdx.x == 0) {
        double tot = 0.0;
#pragma unroll
        for (int w = 0; w < 16; ++w) tot += wsum[w];
        double corr = 0.0;
        for (int r = 0; r < 5; ++r) {
            int idx = winner[r];
            float rr = ret[idx];
            float a = fabsf(rr);
            float strict, mid;
            if (rr < 0.0f)       { strict = 0.005f * a;  mid = 0.0025f * a; }
            else if (rr >= 2.0f) { strict = -0.02f * rr; mid = -0.01f * rr; }
            else if (rr > 0.0f)  { strict = -0.01f * rr; mid = -0.005f * rr; }
            else                 { strict = 0.0f;        mid = 0.0f; }
            float rest = (rr >= 2.0f) ? 0.0015f * rr : 0.0f;
            float bucket = (r < 3) ? strict : mid;  // ranks 1..3 strict, 4..5 mid
            corr += (double)(bucket - rest);
        }
        out[0] = (float)((tot + corr) / (double)n);
    }
}

extern "C" void kernel_launch(void* const* d_in, const int* in_sizes, int n_in,
                              void* d_out, int out_size, void* d_ws, size_t ws_size,
                              hipStream_t stream) {
    const float* pred = (const float*)d_in[0];
    const float* tru  = (const float*)d_in[1];
    const float* ret  = (const float*)d_in[2];
    float* out = (float*)d_out;
    const int n = in_sizes[0];

    int nb = 2048;
    // Per-block scratch: 8B sum + 5*8B candidate keys = 48B. Fit within ws_size.
    while (nb > 64 && (size_t)nb * 48 > ws_size) nb >>= 1;

    double* blk_sum = (double*)d_ws;
    u64*    cand_k  = (u64*)(blk_sum + nb);

    reward_pass1<<<nb, TPB, 0, stream>>>(pred, tru, ret, blk_sum, cand_k, n);
    reward_pass2<<<1, TPB2, 0, stream>>>(blk_sum, cand_k, ret, out, nb, n);
}